// Round 5
// baseline (604.499 us; speedup 1.0000x reference)
//
#include <hip/hip_runtime.h>

#define IN_DIM   256
#define OUT_DIM  128
#define SLOPE    0.1f

// =====================================================================
// GEMM: h = feat[uniq] @ W^T + bias ; fused s_src = h@a_src, s_dst = h@a_dst
// block 256, tile 128 rows x 128 cols (all), K in tiles of 32.
// Register-prefetch pipeline: global loads for tile t+1 are issued before
// the compute phase of tile t, hiding HBM/L2 latency under ~4k cy of FMA.
// =====================================================================
__global__ __launch_bounds__(256) void gemm_h_kernel(
    const float* __restrict__ feat, const float* __restrict__ W,
    const float* __restrict__ bias, const float* __restrict__ avec,
    const int* __restrict__ uniq,
    float* __restrict__ h, float* __restrict__ s_src, float* __restrict__ s_dst,
    int M)
{
  __shared__ float A_lds[32][128];   // [kk][row]  k-major
  __shared__ float B_lds[32][128];   // [kk][col]  k-major
  const int tid = threadIdx.x;
  const int tx = tid & 15, ty = tid >> 4;
  const int m0 = blockIdx.x * 128;
  const int sr = tid & 127;          // staging row (A) / col (B)
  const int q  = tid >> 7;           // which k-half of the tile this thread stages

  const int row_s = m0 + sr;
  const int frow = uniq[row_s < M ? row_s : (M - 1)];
  const float* fbase = feat + (size_t)frow * IN_DIM;
  const float* wbase = W + (size_t)sr * IN_DIM;

  float acc[2][2][4][4];
#pragma unroll
  for (int j = 0; j < 2; ++j)
#pragma unroll
    for (int i = 0; i < 2; ++i)
#pragma unroll
      for (int r = 0; r < 4; ++r)
#pragma unroll
        for (int c = 0; c < 4; ++c) acc[j][i][r][c] = 0.f;

  float4 pa[4], pb[4];               // staged k-tile (regs)
#pragma unroll
  for (int p = 0; p < 4; ++p) {      // prologue: load tile 0
    pa[p] = *(const float4*)(fbase + q * 16 + p * 4);
    pb[p] = *(const float4*)(wbase + q * 16 + p * 4);
  }

  for (int kt = 0; kt < IN_DIM; kt += 32) {
    // regs -> LDS for current tile
#pragma unroll
    for (int p = 0; p < 4; ++p) {
      const int kk = q * 16 + p * 4;
      A_lds[kk + 0][sr] = pa[p].x; A_lds[kk + 1][sr] = pa[p].y;
      A_lds[kk + 2][sr] = pa[p].z; A_lds[kk + 3][sr] = pa[p].w;
      B_lds[kk + 0][sr] = pb[p].x; B_lds[kk + 1][sr] = pb[p].y;
      B_lds[kk + 2][sr] = pb[p].z; B_lds[kk + 3][sr] = pb[p].w;
    }
    __syncthreads();
    // issue next tile's global loads; vmcnt-wait lands at next STORE
    if (kt + 32 < IN_DIM) {
#pragma unroll
      for (int p = 0; p < 4; ++p) {
        pa[p] = *(const float4*)(fbase + kt + 32 + q * 16 + p * 4);
        pb[p] = *(const float4*)(wbase + kt + 32 + q * 16 + p * 4);
      }
    }
#pragma unroll
    for (int kk = 0; kk < 32; ++kk) {
      float4 a0 = *(const float4*)&A_lds[kk][4 * ty];
      float4 a1 = *(const float4*)&A_lds[kk][4 * ty + 64];
      float4 b0 = *(const float4*)&B_lds[kk][4 * tx];
      float4 b1 = *(const float4*)&B_lds[kk][4 * tx + 64];
      float ar[2][4] = {{a0.x, a0.y, a0.z, a0.w}, {a1.x, a1.y, a1.z, a1.w}};
      float br[2][4] = {{b0.x, b0.y, b0.z, b0.w}, {b1.x, b1.y, b1.z, b1.w}};
#pragma unroll
      for (int j = 0; j < 2; ++j)
#pragma unroll
        for (int r = 0; r < 4; ++r)
#pragma unroll
          for (int i = 0; i < 2; ++i)
#pragma unroll
            for (int c = 0; c < 4; ++c)
              acc[j][i][r][c] = fmaf(ar[j][r], br[i][c], acc[j][i][r][c]);
    }
    __syncthreads();
  }

  // epilogue: +bias, store h, fused s_src/s_dst row dot-products
  float4 bb0 = *(const float4*)(bias + 4 * tx);
  float4 bb1 = *(const float4*)(bias + 4 * tx + 64);
  float4 as0 = *(const float4*)(avec + 4 * tx);
  float4 as1 = *(const float4*)(avec + 4 * tx + 64);
  float4 ad0 = *(const float4*)(avec + OUT_DIM + 4 * tx);
  float4 ad1 = *(const float4*)(avec + OUT_DIM + 4 * tx + 64);

#pragma unroll
  for (int j = 0; j < 2; ++j) {
#pragma unroll
    for (int r = 0; r < 4; ++r) {
      const int row = m0 + 4 * ty + 64 * j + r;
      float4 v0, v1;
      v0.x = acc[j][0][r][0] + bb0.x; v0.y = acc[j][0][r][1] + bb0.y;
      v0.z = acc[j][0][r][2] + bb0.z; v0.w = acc[j][0][r][3] + bb0.w;
      v1.x = acc[j][1][r][0] + bb1.x; v1.y = acc[j][1][r][1] + bb1.y;
      v1.z = acc[j][1][r][2] + bb1.z; v1.w = acc[j][1][r][3] + bb1.w;
      float ps = v0.x * as0.x + v0.y * as0.y + v0.z * as0.z + v0.w * as0.w
               + v1.x * as1.x + v1.y * as1.y + v1.z * as1.z + v1.w * as1.w;
      float pd = v0.x * ad0.x + v0.y * ad0.y + v0.z * ad0.z + v0.w * ad0.w
               + v1.x * ad1.x + v1.y * ad1.y + v1.z * ad1.z + v1.w * ad1.w;
#pragma unroll
      for (int d = 1; d < 16; d <<= 1) {
        ps += __shfl_xor(ps, d, 64);
        pd += __shfl_xor(pd, d, 64);
      }
      if (row < M) {
        *(float4*)(h + (size_t)row * OUT_DIM + 4 * tx) = v0;
        *(float4*)(h + (size_t)row * OUT_DIM + 4 * tx + 64) = v1;
        if (tx == 0) { s_src[row] = ps; s_dst[row] = pd; }
      }
    }
  }
}

// =====================================================================
// CSR build (merged): hist -> scan1 -> scan2 -> scan3 -> scatter
// Both the edge-CSR (deg/offs/csr) and the output-row CSR
// (odeg/ooff/orows) flow through the SAME dispatches.
// =====================================================================
__global__ __launch_bounds__(256) void hist_kernel(const int* __restrict__ edges,
                                                   const int* __restrict__ nidx,
                                                   int* __restrict__ deg,
                                                   int* __restrict__ odeg,
                                                   int E, int B) {
  int i = blockIdx.x * 256 + threadIdx.x;
  if (i < E) atomicAdd(&deg[((const int2*)edges)[i].x], 1);
  if (i < B) atomicAdd(&odeg[nidx[i]], 1);
}

// per-chunk (1024) sums; blocks [0,NB) -> deg/bsum, [NB,2NB) -> odeg/obsum
__global__ __launch_bounds__(256) void scan1_kernel(const int* __restrict__ deg,
                                                    const int* __restrict__ odeg,
                                                    int* __restrict__ bsum,
                                                    int* __restrict__ obsum, int NB) {
  const int tid = threadIdx.x;
  const bool second = blockIdx.x >= NB;
  const int blk = second ? blockIdx.x - NB : blockIdx.x;
  const int* src = second ? odeg : deg;
  int* dst = second ? obsum : bsum;
  const int base = blk * 1024 + tid * 4;
  int4 v = *(const int4*)(src + base);     // padded+zeroed, safe
  int s = v.x + v.y + v.z + v.w;
#pragma unroll
  for (int d = 32; d > 0; d >>= 1) s += __shfl_down(s, d, 64);
  __shared__ int red[4];
  if ((tid & 63) == 0) red[tid >> 6] = s;
  __syncthreads();
  if (tid == 0) dst[blk] = red[0] + red[1] + red[2] + red[3];
}

// exclusive scan of both chunk-sum arrays (nb <= 256) in one block;
// tid 0 (wave 0) handles deg-side, tid 64 (wave 1) handles odeg-side.
__global__ __launch_bounds__(256) void scan2_kernel(const int* __restrict__ bsum,
                                                    const int* __restrict__ obsum,
                                                    int* __restrict__ boff,
                                                    int* __restrict__ oboff, int nb,
                                                    int* __restrict__ off_n,
                                                    int* __restrict__ ooff_n) {
  __shared__ int sa[256], sb[256];
  const int tid = threadIdx.x;
  sa[tid] = (tid < nb) ? bsum[tid] : 0;
  sb[tid] = (tid < nb) ? obsum[tid] : 0;
  __syncthreads();
  if (tid == 0) {
    int run = 0;
    for (int i = 0; i < nb; ++i) { int t = sa[i]; boff[i] = run; run += t; }
    *off_n = run;
  }
  if (tid == 64) {
    int run = 0;
    for (int i = 0; i < nb; ++i) { int t = sb[i]; oboff[i] = run; run += t; }
    *ooff_n = run;
  }
}

// per-chunk exclusive scan + chunk base; also initializes the scatter
// cursors to the absolute base offsets (cursor trick: no zeroing memset,
// scatter's atomicAdd then returns the final absolute slot directly).
__global__ __launch_bounds__(256) void scan3_kernel(const int* __restrict__ deg,
                                                    const int* __restrict__ odeg,
                                                    const int* __restrict__ boff,
                                                    const int* __restrict__ oboff,
                                                    int* __restrict__ offs,
                                                    int* __restrict__ ooff,
                                                    int* __restrict__ cursor,
                                                    int* __restrict__ ocur,
                                                    int NB, int n) {
  __shared__ int sh[256];
  const int tid = threadIdx.x;
  const bool second = blockIdx.x >= NB;
  const int blk = second ? blockIdx.x - NB : blockIdx.x;
  const int* src  = second ? odeg : deg;
  const int* bofp = second ? oboff : boff;
  int* offp = second ? ooff : offs;
  int* curp = second ? ocur : cursor;

  const int base = blk * 1024 + tid * 4;
  int4 v = *(const int4*)(src + base);
  const int tot = v.x + v.y + v.z + v.w;
  sh[tid] = tot;
  __syncthreads();
  int run = tot;
#pragma unroll
  for (int st = 1; st < 256; st <<= 1) {
    int other = (tid >= st) ? sh[tid - st] : 0;
    __syncthreads();
    run += other;
    sh[tid] = run;
    __syncthreads();
  }
  int excl = run - tot + bofp[blk];
  int o0 = excl, o1 = o0 + v.x, o2 = o1 + v.y, o3 = o2 + v.z;
  if (base + 0 < n) { offp[base + 0] = o0; curp[base + 0] = o0; }
  if (base + 1 < n) { offp[base + 1] = o1; curp[base + 1] = o1; }
  if (base + 2 < n) { offp[base + 2] = o2; curp[base + 2] = o2; }
  if (base + 3 < n) { offp[base + 3] = o3; curp[base + 3] = o3; }
}

__global__ __launch_bounds__(256) void scatter_kernel(const int* __restrict__ edges,
                                                      const int* __restrict__ nidx,
                                                      int* __restrict__ cursor,
                                                      int* __restrict__ ocur,
                                                      int* __restrict__ csr_dst,
                                                      int* __restrict__ orows,
                                                      int E, int B) {
  int i = blockIdx.x * 256 + threadIdx.x;
  if (i < E) {
    int2 e = ((const int2*)edges)[i];
    int pos = atomicAdd(&cursor[e.x], 1);   // absolute slot (cursor = base)
    csr_dst[pos] = e.y;
  }
  if (i < B) {
    int n = nidx[i];
    int pos = atomicAdd(&ocur[n], 1);
    orows[pos] = i;
  }
}

// =====================================================================
// Aggregation: one 32-lane group per src node (2 nodes/wave); skip nodes
// not referenced by node_idx. Lane holds cols {4*lane .. 4*lane+3} (float4).
// Unroll-4: four independent csr->(s_dst,h) gather chains in flight.
// Writes final output rows directly.
// =====================================================================
__global__ __launch_bounds__(256) void aggregate_kernel(
    const float* __restrict__ h, const float* __restrict__ s_src,
    const float* __restrict__ s_dst, const int* __restrict__ offsets,
    const int* __restrict__ csr_dst, const int* __restrict__ ooff,
    const int* __restrict__ orows, float* __restrict__ out, int N)
{
  const int gw = (blockIdx.x * 256 + threadIdx.x) >> 5;   // 32-lane group id
  const int lane = threadIdx.x & 31;
  if (gw >= N) return;
  const int ob = ooff[gw], oe = ooff[gw + 1];
  if (ob == oe) return;                       // node never read by output

  const int beg = offsets[gw], end = offsets[gw + 1];
  const float ssrc = s_src[gw];
  const float4* hp = (const float4*)h;        // one h row = 32 float4

  float ax = 0.f, ay = 0.f, az = 0.f, aw = 0.f, den = 0.f;
  int i = beg;
  for (; i + 4 <= end; i += 4) {
    int d0 = csr_dst[i], d1 = csr_dst[i + 1];
    int d2 = csr_dst[i + 2], d3 = csr_dst[i + 3];
    float z0 = ssrc + s_dst[d0];
    float z1 = ssrc + s_dst[d1];
    float z2 = ssrc + s_dst[d2];
    float z3 = ssrc + s_dst[d3];
    float4 h0 = hp[(size_t)d0 * 32 + lane];
    float4 h1 = hp[(size_t)d1 * 32 + lane];
    float4 h2 = hp[(size_t)d2 * 32 + lane];
    float4 h3 = hp[(size_t)d3 * 32 + lane];
    z0 = z0 > 0.f ? z0 : z0 * SLOPE;
    z1 = z1 > 0.f ? z1 : z1 * SLOPE;
    z2 = z2 > 0.f ? z2 : z2 * SLOPE;
    z3 = z3 > 0.f ? z3 : z3 * SLOPE;
    float e0 = __expf(z0), e1 = __expf(z1);
    float e2 = __expf(z2), e3 = __expf(z3);
    den += (e0 + e1) + (e2 + e3);
    ax = fmaf(e0, h0.x, ax); ay = fmaf(e0, h0.y, ay);
    az = fmaf(e0, h0.z, az); aw = fmaf(e0, h0.w, aw);
    ax = fmaf(e1, h1.x, ax); ay = fmaf(e1, h1.y, ay);
    az = fmaf(e1, h1.z, az); aw = fmaf(e1, h1.w, aw);
    ax = fmaf(e2, h2.x, ax); ay = fmaf(e2, h2.y, ay);
    az = fmaf(e2, h2.z, az); aw = fmaf(e2, h2.w, aw);
    ax = fmaf(e3, h3.x, ax); ay = fmaf(e3, h3.y, ay);
    az = fmaf(e3, h3.z, az); aw = fmaf(e3, h3.w, aw);
  }
  for (; i + 2 <= end; i += 2) {
    int d0 = csr_dst[i], d1 = csr_dst[i + 1];
    float z0 = ssrc + s_dst[d0];
    float z1 = ssrc + s_dst[d1];
    float4 h0 = hp[(size_t)d0 * 32 + lane];
    float4 h1 = hp[(size_t)d1 * 32 + lane];
    z0 = z0 > 0.f ? z0 : z0 * SLOPE;
    z1 = z1 > 0.f ? z1 : z1 * SLOPE;
    float e0 = __expf(z0), e1 = __expf(z1);
    den += e0 + e1;
    ax = fmaf(e0, h0.x, ax); ay = fmaf(e0, h0.y, ay);
    az = fmaf(e0, h0.z, az); aw = fmaf(e0, h0.w, aw);
    ax = fmaf(e1, h1.x, ax); ay = fmaf(e1, h1.y, ay);
    az = fmaf(e1, h1.z, az); aw = fmaf(e1, h1.w, aw);
  }
  if (i < end) {
    int d0 = csr_dst[i];
    float z0 = ssrc + s_dst[d0];
    float4 h0 = hp[(size_t)d0 * 32 + lane];
    z0 = z0 > 0.f ? z0 : z0 * SLOPE;
    float e0 = __expf(z0);
    den += e0;
    ax = fmaf(e0, h0.x, ax); ay = fmaf(e0, h0.y, ay);
    az = fmaf(e0, h0.z, az); aw = fmaf(e0, h0.w, aw);
  }
  const float inv = 1.f / den;
  float4 o; o.x = ax * inv; o.y = ay * inv; o.z = az * inv; o.w = aw * inv;
  for (int j = ob; j < oe; ++j) {
    ((float4*)out)[(size_t)orows[j] * 32 + lane] = o;
  }
}

// =====================================================================
extern "C" void kernel_launch(void* const* d_in, const int* in_sizes, int n_in,
                              void* d_out, int out_size, void* d_ws, size_t ws_size,
                              hipStream_t stream) {
  const float* feat = (const float*)d_in[0];
  const float* W    = (const float*)d_in[1];
  const float* bias = (const float*)d_in[2];
  const float* avec = (const float*)d_in[3];
  const int*   edges = (const int*)d_in[4];
  const int*   uniq  = (const int*)d_in[5];
  const int*   nidx  = (const int*)d_in[6];
  float* out = (float*)d_out;

  const int E = in_sizes[4] / 2;
  const int N = in_sizes[5];
  const int B = in_sizes[6];
  const int NB   = (N + 1023) / 1024;
  const int NPAD = NB * 1024;

  char* p = (char*)d_ws;
  auto alloc = [&](size_t bytes) -> void* {
    void* r = (void*)p;
    p += (bytes + 511) & ~(size_t)511;
    return r;
  };
  float* h    = (float*)alloc((size_t)N * OUT_DIM * 4);
  float* ssrc = (float*)alloc((size_t)N * 4);
  float* sdst = (float*)alloc((size_t)N * 4);
  // deg + odeg contiguous -> one zeroing memset covers both
  int* deg    = (int*)alloc((size_t)2 * NPAD * 4);
  int* odeg   = deg + NPAD;
  int* cursor = (int*)alloc((size_t)N * 4);    // init'd by scan3, no memset
  int* ocur   = (int*)alloc((size_t)N * 4);    // init'd by scan3, no memset
  int* offs   = (int*)alloc((size_t)(N + 1) * 4);
  int* ooff   = (int*)alloc((size_t)(N + 1) * 4);
  int* bsum   = (int*)alloc((size_t)NB * 4);
  int* obsum  = (int*)alloc((size_t)NB * 4);
  int* boff   = (int*)alloc((size_t)NB * 4);
  int* oboff  = (int*)alloc((size_t)NB * 4);
  int* csr    = (int*)alloc((size_t)E * 4);
  int* orows  = (int*)alloc((size_t)B * 4);

  hipMemsetAsync(deg, 0, (size_t)2 * NPAD * 4, stream);

  gemm_h_kernel<<<(N + 127) / 128, 256, 0, stream>>>(feat, W, bias, avec, uniq,
                                                     h, ssrc, sdst, N);

  hist_kernel<<<(E + 255) / 256, 256, 0, stream>>>(edges, nidx, deg, odeg, E, B);
  scan1_kernel<<<2 * NB, 256, 0, stream>>>(deg, odeg, bsum, obsum, NB);
  scan2_kernel<<<1, 256, 0, stream>>>(bsum, obsum, boff, oboff, NB,
                                      offs + N, ooff + N);
  scan3_kernel<<<2 * NB, 256, 0, stream>>>(deg, odeg, boff, oboff, offs, ooff,
                                           cursor, ocur, NB, N);
  scatter_kernel<<<(E + 255) / 256, 256, 0, stream>>>(edges, nidx, cursor, ocur,
                                                      csr, orows, E, B);

  aggregate_kernel<<<(N * 32 + 255) / 256, 256, 0, stream>>>(h, ssrc, sdst, offs, csr,
                                                             ooff, orows, out, N);
}

// Round 6
// 569.714 us; speedup vs baseline: 1.0611x; 1.0611x over previous
//
#include <hip/hip_runtime.h>

#define IN_DIM   256
#define OUT_DIM  128
#define SLOPE    0.1f

typedef short short8 __attribute__((ext_vector_type(8)));
typedef float f32x4  __attribute__((ext_vector_type(4)));

// split one float into hi(bf16) + lo(bf16(x - hi)), RNE rounding
__device__ __forceinline__ void cvt_split8(const float4 a, const float4 b,
                                           short8& H, short8& L) {
  float x[8] = {a.x, a.y, a.z, a.w, b.x, b.y, b.z, b.w};
  short hs[8], ls[8];
#pragma unroll
  for (int i = 0; i < 8; ++i) {
    unsigned u  = __float_as_uint(x[i]);
    unsigned uh = (u + 0x7FFFu + ((u >> 16) & 1u)) & 0xFFFF0000u;
    float fh = __uint_as_float(uh);
    float rl = x[i] - fh;
    unsigned ul = __float_as_uint(rl);
    unsigned hl = (ul + 0x7FFFu + ((ul >> 16) & 1u)) >> 16;
    hs[i] = (short)(uh >> 16);
    ls[i] = (short)hl;
  }
  H = short8{hs[0], hs[1], hs[2], hs[3], hs[4], hs[5], hs[6], hs[7]};
  L = short8{ls[0], ls[1], ls[2], ls[3], ls[4], ls[5], ls[6], ls[7]};
}

// =====================================================================
// W pre-pack: W[128][256] fp32 -> per-lane MFMA B-fragments, hi/lo bf16.
// slot = (s*8 + f)*64 + l  holds W[col = f*16 + (l&15)][k = s*32 + (l>>4)*8 + r]
// =====================================================================
__global__ __launch_bounds__(256) void wpack_kernel(const float* __restrict__ W,
                                                    short8* __restrict__ Wh,
                                                    short8* __restrict__ Wl) {
  const int slot = blockIdx.x * 256 + threadIdx.x;   // grid 16 -> 4096 slots
  const int sf = slot >> 6;          // s*8 + f
  const int l  = slot & 63;
  const int col = (sf & 7) * 16 + (l & 15);
  const int k0  = (sf >> 3) * 32 + (l >> 4) * 8;
  const float4* p = (const float4*)(W + (size_t)col * IN_DIM + k0);
  short8 H, L;
  cvt_split8(p[0], p[1], H, L);
  Wh[slot] = H;
  Wl[slot] = L;
}

// =====================================================================
// GEMM via split-bf16 MFMA: h = feat[uniq] @ W^T + bias, fused s_src/s_dst.
// block 256 = 4 waves; tile 128 rows; wave w owns rows [w*32, w*32+32),
// all 128 cols (2 m-frags x 8 n-frags of 16x16, acc 64 f32/lane).
// K in steps of 32 (one mfma K). A staged frag-packed in LDS (hi+lo),
// B fragments loaded straight from pre-packed global (L1/L2-resident).
// D = Ah*Bh + Al*Bh + Ah*Bl  (split product, ~fp32 accuracy).
// =====================================================================
__global__ __launch_bounds__(256) void gemm_h_kernel(
    const float* __restrict__ feat, const short8* __restrict__ Wh,
    const short8* __restrict__ Wl, const float* __restrict__ bias,
    const float* __restrict__ avec, const int* __restrict__ uniq,
    float* __restrict__ h, float* __restrict__ s_src, float* __restrict__ s_dst,
    int M)
{
  __shared__ short8 Ah[512];   // 8 frags x 64 lanes, 16 B each (8 KB)
  __shared__ short8 Al[512];
  const int tid = threadIdx.x;
  const int w = tid >> 6;            // wave 0..3
  const int l = tid & 63;
  const int c = l & 15, g = l >> 4;
  const int m0 = blockIdx.x * 128;

  // staging role: thread stages 16 floats of one row's k-slice
  const int srow = tid >> 1, kseg = tid & 1;
  const int frow = uniq[min(m0 + srow, M - 1)];
  const float4* fb = (const float4*)(feat + (size_t)frow * IN_DIM) + kseg * 4;
  const int slot0 = (srow >> 4) * 64 + (srow & 15) + 32 * kseg;

  f32x4 acc[2][8] = {};

  float4 pa0 = fb[0], pa1 = fb[1], pa2 = fb[2], pa3 = fb[3];
  float4 na0, na1, na2, na3;

  for (int s = 0; s < 8; ++s) {
    short8 H0, L0, H1, L1;
    cvt_split8(pa0, pa1, H0, L0);
    cvt_split8(pa2, pa3, H1, L1);
    Ah[slot0] = H0; Ah[slot0 + 16] = H1;
    Al[slot0] = L0; Al[slot0 + 16] = L1;
    __syncthreads();
    if (s < 7) {                      // prefetch next k-slice during compute
      const float4* nb = fb + (s + 1) * 8;
      na0 = nb[0]; na1 = nb[1]; na2 = nb[2]; na3 = nb[3];
    }
    short8 a0h = Ah[(w * 2 + 0) * 64 + l], a0l = Al[(w * 2 + 0) * 64 + l];
    short8 a1h = Ah[(w * 2 + 1) * 64 + l], a1l = Al[(w * 2 + 1) * 64 + l];
    const short8* wh = Wh + s * 512 + l;
    const short8* wl = Wl + s * 512 + l;
#pragma unroll
    for (int n = 0; n < 8; ++n) {
      short8 bh = wh[n * 64];
      short8 bl = wl[n * 64];
      acc[0][n] = __builtin_amdgcn_mfma_f32_16x16x32_bf16(a0h, bh, acc[0][n], 0, 0, 0);
      acc[1][n] = __builtin_amdgcn_mfma_f32_16x16x32_bf16(a1h, bh, acc[1][n], 0, 0, 0);
      acc[0][n] = __builtin_amdgcn_mfma_f32_16x16x32_bf16(a0l, bh, acc[0][n], 0, 0, 0);
      acc[1][n] = __builtin_amdgcn_mfma_f32_16x16x32_bf16(a1l, bh, acc[1][n], 0, 0, 0);
      acc[0][n] = __builtin_amdgcn_mfma_f32_16x16x32_bf16(a0h, bl, acc[0][n], 0, 0, 0);
      acc[1][n] = __builtin_amdgcn_mfma_f32_16x16x32_bf16(a1h, bl, acc[1][n], 0, 0, 0);
    }
    __syncthreads();
    pa0 = na0; pa1 = na1; pa2 = na2; pa3 = na3;
  }

  // epilogue: +bias, store h, fused s_src/s_dst (16-lane shfl reduce)
  float bias_v[8], as_v[8], ad_v[8];
#pragma unroll
  for (int n = 0; n < 8; ++n) {
    bias_v[n] = bias[n * 16 + c];
    as_v[n]   = avec[n * 16 + c];
    ad_v[n]   = avec[OUT_DIM + n * 16 + c];
  }
#pragma unroll
  for (int m = 0; m < 2; ++m) {
#pragma unroll
    for (int r = 0; r < 4; ++r) {
      const int grow = m0 + w * 32 + m * 16 + g * 4 + r;
      const bool ok = grow < M;
      float ps = 0.f, pd = 0.f;
#pragma unroll
      for (int n = 0; n < 8; ++n) {
        float v = acc[m][n][r] + bias_v[n];
        if (ok) h[(size_t)grow * OUT_DIM + n * 16 + c] = v;
        ps = fmaf(v, as_v[n], ps);
        pd = fmaf(v, ad_v[n], pd);
      }
#pragma unroll
      for (int d = 1; d < 16; d <<= 1) {
        ps += __shfl_xor(ps, d, 64);
        pd += __shfl_xor(pd, d, 64);
      }
      if (ok && c == 0) { s_src[grow] = ps; s_dst[grow] = pd; }
    }
  }
}

// =====================================================================
// CSR build (merged): hist -> scan1 -> scan2 -> scan3 -> scatter
// =====================================================================
__global__ __launch_bounds__(256) void hist_kernel(const int* __restrict__ edges,
                                                   const int* __restrict__ nidx,
                                                   int* __restrict__ deg,
                                                   int* __restrict__ odeg,
                                                   int E, int B) {
  int i = blockIdx.x * 256 + threadIdx.x;
  if (i < E) atomicAdd(&deg[((const int2*)edges)[i].x], 1);
  if (i < B) atomicAdd(&odeg[nidx[i]], 1);
}

__global__ __launch_bounds__(256) void scan1_kernel(const int* __restrict__ deg,
                                                    const int* __restrict__ odeg,
                                                    int* __restrict__ bsum,
                                                    int* __restrict__ obsum, int NB) {
  const int tid = threadIdx.x;
  const bool second = blockIdx.x >= NB;
  const int blk = second ? blockIdx.x - NB : blockIdx.x;
  const int* src = second ? odeg : deg;
  int* dst = second ? obsum : bsum;
  const int base = blk * 1024 + tid * 4;
  int4 v = *(const int4*)(src + base);
  int s = v.x + v.y + v.z + v.w;
#pragma unroll
  for (int d = 32; d > 0; d >>= 1) s += __shfl_down(s, d, 64);
  __shared__ int red[4];
  if ((tid & 63) == 0) red[tid >> 6] = s;
  __syncthreads();
  if (tid == 0) dst[blk] = red[0] + red[1] + red[2] + red[3];
}

__global__ __launch_bounds__(256) void scan2_kernel(const int* __restrict__ bsum,
                                                    const int* __restrict__ obsum,
                                                    int* __restrict__ boff,
                                                    int* __restrict__ oboff, int nb,
                                                    int* __restrict__ off_n,
                                                    int* __restrict__ ooff_n) {
  __shared__ int sa[256], sb[256];
  const int tid = threadIdx.x;
  sa[tid] = (tid < nb) ? bsum[tid] : 0;
  sb[tid] = (tid < nb) ? obsum[tid] : 0;
  __syncthreads();
  if (tid == 0) {
    int run = 0;
    for (int i = 0; i < nb; ++i) { int t = sa[i]; boff[i] = run; run += t; }
    *off_n = run;
  }
  if (tid == 64) {
    int run = 0;
    for (int i = 0; i < nb; ++i) { int t = sb[i]; oboff[i] = run; run += t; }
    *ooff_n = run;
  }
}

__global__ __launch_bounds__(256) void scan3_kernel(const int* __restrict__ deg,
                                                    const int* __restrict__ odeg,
                                                    const int* __restrict__ boff,
                                                    const int* __restrict__ oboff,
                                                    int* __restrict__ offs,
                                                    int* __restrict__ ooff,
                                                    int* __restrict__ cursor,
                                                    int* __restrict__ ocur,
                                                    int NB, int n) {
  __shared__ int sh[256];
  const int tid = threadIdx.x;
  const bool second = blockIdx.x >= NB;
  const int blk = second ? blockIdx.x - NB : blockIdx.x;
  const int* src  = second ? odeg : deg;
  const int* bofp = second ? oboff : boff;
  int* offp = second ? ooff : offs;
  int* curp = second ? ocur : cursor;

  const int base = blk * 1024 + tid * 4;
  int4 v = *(const int4*)(src + base);
  const int tot = v.x + v.y + v.z + v.w;
  sh[tid] = tot;
  __syncthreads();
  int run = tot;
#pragma unroll
  for (int st = 1; st < 256; st <<= 1) {
    int other = (tid >= st) ? sh[tid - st] : 0;
    __syncthreads();
    run += other;
    sh[tid] = run;
    __syncthreads();
  }
  int excl = run - tot + bofp[blk];
  int o0 = excl, o1 = o0 + v.x, o2 = o1 + v.y, o3 = o2 + v.z;
  if (base + 0 < n) { offp[base + 0] = o0; curp[base + 0] = o0; }
  if (base + 1 < n) { offp[base + 1] = o1; curp[base + 1] = o1; }
  if (base + 2 < n) { offp[base + 2] = o2; curp[base + 2] = o2; }
  if (base + 3 < n) { offp[base + 3] = o3; curp[base + 3] = o3; }
}

__global__ __launch_bounds__(256) void scatter_kernel(const int* __restrict__ edges,
                                                      const int* __restrict__ nidx,
                                                      int* __restrict__ cursor,
                                                      int* __restrict__ ocur,
                                                      int* __restrict__ csr_dst,
                                                      int* __restrict__ orows,
                                                      int E, int B) {
  int i = blockIdx.x * 256 + threadIdx.x;
  if (i < E) {
    int2 e = ((const int2*)edges)[i];
    int pos = atomicAdd(&cursor[e.x], 1);   // absolute slot (cursor = base)
    csr_dst[pos] = e.y;
  }
  if (i < B) {
    int n = nidx[i];
    int pos = atomicAdd(&ocur[n], 1);
    orows[pos] = i;
  }
}

// =====================================================================
// Aggregation: one 32-lane group per src node; skip nodes with no output.
// =====================================================================
__global__ __launch_bounds__(256) void aggregate_kernel(
    const float* __restrict__ h, const float* __restrict__ s_src,
    const float* __restrict__ s_dst, const int* __restrict__ offsets,
    const int* __restrict__ csr_dst, const int* __restrict__ ooff,
    const int* __restrict__ orows, float* __restrict__ out, int N)
{
  const int gw = (blockIdx.x * 256 + threadIdx.x) >> 5;
  const int lane = threadIdx.x & 31;
  if (gw >= N) return;
  const int ob = ooff[gw], oe = ooff[gw + 1];
  if (ob == oe) return;

  const int beg = offsets[gw], end = offsets[gw + 1];
  const float ssrc = s_src[gw];
  const float4* hp = (const float4*)h;

  float ax = 0.f, ay = 0.f, az = 0.f, aw = 0.f, den = 0.f;
  int i = beg;
  for (; i + 4 <= end; i += 4) {
    int d0 = csr_dst[i], d1 = csr_dst[i + 1];
    int d2 = csr_dst[i + 2], d3 = csr_dst[i + 3];
    float z0 = ssrc + s_dst[d0];
    float z1 = ssrc + s_dst[d1];
    float z2 = ssrc + s_dst[d2];
    float z3 = ssrc + s_dst[d3];
    float4 h0 = hp[(size_t)d0 * 32 + lane];
    float4 h1 = hp[(size_t)d1 * 32 + lane];
    float4 h2 = hp[(size_t)d2 * 32 + lane];
    float4 h3 = hp[(size_t)d3 * 32 + lane];
    z0 = z0 > 0.f ? z0 : z0 * SLOPE;
    z1 = z1 > 0.f ? z1 : z1 * SLOPE;
    z2 = z2 > 0.f ? z2 : z2 * SLOPE;
    z3 = z3 > 0.f ? z3 : z3 * SLOPE;
    float e0 = __expf(z0), e1 = __expf(z1);
    float e2 = __expf(z2), e3 = __expf(z3);
    den += (e0 + e1) + (e2 + e3);
    ax = fmaf(e0, h0.x, ax); ay = fmaf(e0, h0.y, ay);
    az = fmaf(e0, h0.z, az); aw = fmaf(e0, h0.w, aw);
    ax = fmaf(e1, h1.x, ax); ay = fmaf(e1, h1.y, ay);
    az = fmaf(e1, h1.z, az); aw = fmaf(e1, h1.w, aw);
    ax = fmaf(e2, h2.x, ax); ay = fmaf(e2, h2.y, ay);
    az = fmaf(e2, h2.z, az); aw = fmaf(e2, h2.w, aw);
    ax = fmaf(e3, h3.x, ax); ay = fmaf(e3, h3.y, ay);
    az = fmaf(e3, h3.z, az); aw = fmaf(e3, h3.w, aw);
  }
  for (; i + 2 <= end; i += 2) {
    int d0 = csr_dst[i], d1 = csr_dst[i + 1];
    float z0 = ssrc + s_dst[d0];
    float z1 = ssrc + s_dst[d1];
    float4 h0 = hp[(size_t)d0 * 32 + lane];
    float4 h1 = hp[(size_t)d1 * 32 + lane];
    z0 = z0 > 0.f ? z0 : z0 * SLOPE;
    z1 = z1 > 0.f ? z1 : z1 * SLOPE;
    float e0 = __expf(z0), e1 = __expf(z1);
    den += e0 + e1;
    ax = fmaf(e0, h0.x, ax); ay = fmaf(e0, h0.y, ay);
    az = fmaf(e0, h0.z, az); aw = fmaf(e0, h0.w, aw);
    ax = fmaf(e1, h1.x, ax); ay = fmaf(e1, h1.y, ay);
    az = fmaf(e1, h1.z, az); aw = fmaf(e1, h1.w, aw);
  }
  if (i < end) {
    int d0 = csr_dst[i];
    float z0 = ssrc + s_dst[d0];
    float4 h0 = hp[(size_t)d0 * 32 + lane];
    z0 = z0 > 0.f ? z0 : z0 * SLOPE;
    float e0 = __expf(z0);
    den += e0;
    ax = fmaf(e0, h0.x, ax); ay = fmaf(e0, h0.y, ay);
    az = fmaf(e0, h0.z, az); aw = fmaf(e0, h0.w, aw);
  }
  const float inv = 1.f / den;
  float4 o; o.x = ax * inv; o.y = ay * inv; o.z = az * inv; o.w = aw * inv;
  for (int j = ob; j < oe; ++j) {
    ((float4*)out)[(size_t)orows[j] * 32 + lane] = o;
  }
}

// =====================================================================
extern "C" void kernel_launch(void* const* d_in, const int* in_sizes, int n_in,
                              void* d_out, int out_size, void* d_ws, size_t ws_size,
                              hipStream_t stream) {
  const float* feat = (const float*)d_in[0];
  const float* W    = (const float*)d_in[1];
  const float* bias = (const float*)d_in[2];
  const float* avec = (const float*)d_in[3];
  const int*   edges = (const int*)d_in[4];
  const int*   uniq  = (const int*)d_in[5];
  const int*   nidx  = (const int*)d_in[6];
  float* out = (float*)d_out;

  const int E = in_sizes[4] / 2;
  const int N = in_sizes[5];
  const int B = in_sizes[6];
  const int NB   = (N + 1023) / 1024;
  const int NPAD = NB * 1024;

  char* p = (char*)d_ws;
  auto alloc = [&](size_t bytes) -> void* {
    void* r = (void*)p;
    p += (bytes + 511) & ~(size_t)511;
    return r;
  };
  float* h    = (float*)alloc((size_t)N * OUT_DIM * 4);
  float* ssrc = (float*)alloc((size_t)N * 4);
  float* sdst = (float*)alloc((size_t)N * 4);
  short8* Whp = (short8*)alloc((size_t)4096 * 16);
  short8* Wlp = (short8*)alloc((size_t)4096 * 16);
  int* deg    = (int*)alloc((size_t)2 * NPAD * 4);
  int* odeg   = deg + NPAD;
  int* cursor = (int*)alloc((size_t)N * 4);
  int* ocur   = (int*)alloc((size_t)N * 4);
  int* offs   = (int*)alloc((size_t)(N + 1) * 4);
  int* ooff   = (int*)alloc((size_t)(N + 1) * 4);
  int* bsum   = (int*)alloc((size_t)NB * 4);
  int* obsum  = (int*)alloc((size_t)NB * 4);
  int* boff   = (int*)alloc((size_t)NB * 4);
  int* oboff  = (int*)alloc((size_t)NB * 4);
  int* csr    = (int*)alloc((size_t)E * 4);
  int* orows  = (int*)alloc((size_t)B * 4);

  hipMemsetAsync(deg, 0, (size_t)2 * NPAD * 4, stream);

  wpack_kernel<<<16, 256, 0, stream>>>(W, Whp, Wlp);
  gemm_h_kernel<<<(N + 127) / 128, 256, 0, stream>>>(feat, Whp, Wlp, bias, avec,
                                                     uniq, h, ssrc, sdst, N);

  hist_kernel<<<(E + 255) / 256, 256, 0, stream>>>(edges, nidx, deg, odeg, E, B);
  scan1_kernel<<<2 * NB, 256, 0, stream>>>(deg, odeg, bsum, obsum, NB);
  scan2_kernel<<<1, 256, 0, stream>>>(bsum, obsum, boff, oboff, NB,
                                      offs + N, ooff + N);
  scan3_kernel<<<2 * NB, 256, 0, stream>>>(deg, odeg, boff, oboff, offs, ooff,
                                           cursor, ocur, NB, N);
  scatter_kernel<<<(E + 255) / 256, 256, 0, stream>>>(edges, nidx, cursor, ocur,
                                                      csr, orows, E, B);

  aggregate_kernel<<<(N * 32 + 255) / 256, 256, 0, stream>>>(h, ssrc, sdst, offs, csr,
                                                             ooff, orows, out, N);
}